// Round 4
// baseline (39.480 us; speedup 1.0000x reference)
//
#include <hip/hip_runtime.h>

// Problem constants (from reference)
#define BATCH 16
#define NSEG 32
#define HW (512 * 1024)              // 524288 pixels per batch (2^19)
#define MIN_PIX 50.0f

// Accum kernel: 1-wave blocks; lane-pair component split.
// Even lane row holds (cnt, su); odd lane row holds (sv, u^2+v^2).
#define THREADS 64
#define BLOCKS_PER_BATCH 128         // grid = 2048 blocks = 8/CU
#define ITERS 16                     // 16 tiles of 256 px per block
#define VEC 4
#define ROWW 34                      // 32 segs + dummy slot (idx 32) + pad

// Accumulator layout in d_ws: acc[b][s][4], comp: 0=cnt 1=su 2=sv 3=s2
#define ACC_FLOATS (BATCH * NSEG * 4)

__global__ __launch_bounds__(THREADS) void ovl_accum(
    const float* __restrict__ flow,   // [B, 2, H, W]
    const int* __restrict__ masks,    // [B, H, W]
    float* __restrict__ acc)          // [B, S, 4], pre-zeroed
{
    __shared__ float2 bins[THREADS][ROWW];   // 17408 B -> 9 blocks/CU

    const int tid = threadIdx.x;
    #pragma unroll
    for (int j = 0; j < ROWW; ++j)
        bins[tid][j] = make_float2(0.0f, 0.0f);
    // single wave per block: lockstep, no barrier needed

    const int b  = blockIdx.x >> 7;                      // batch
    const int bk = blockIdx.x & (BLOCKS_PER_BATCH - 1);  // block within batch
    const float* __restrict__ u_base = flow + (size_t)b * 2 * HW;
    const float* __restrict__ v_base = u_base + HW;
    const int*   __restrict__ m_base = masks + (size_t)b * HW;
    const int par = tid & 1;

#define LOADP(S, IT) { const int p = ((IT) * BLOCKS_PER_BATCH + bk) * (THREADS * VEC) + tid * VEC; \
        m##S = *(const int4*)(m_base + p);                                                         \
        u##S = *(const float4*)(u_base + p);                                                       \
        v##S = *(const float4*)(v_base + p); }

// One pixel per lane per round; lane pair (2i, 2i+1) exchanges so each lane
// updates ITS components for BOTH pixels. Parallel-issued RMWs are made
// race-free by merging duplicate segments and redirecting the dup to slot 32.
#define ROUND(ss, uu, vv) {                                                    \
        const int   s  = (ss) & (NSEG - 1);                                    \
        const float u  = (uu), v = (vv);                                       \
        const int   sp = __shfl_xor(s, 1, 64);                                 \
        const float up = __shfl_xor(u, 1, 64);                                 \
        const float vp = __shfl_xor(v, 1, 64);                                 \
        float2 dS, dP;                                                         \
        dS.x = par ? v  : 1.0f;  dS.y = par ? (u * u + v * v)    : u;          \
        dP.x = par ? vp : 1.0f;  dP.y = par ? (up * up + vp * vp) : up;        \
        const bool dup = (s == sp);                                            \
        if (dup) { dS.x += dP.x; dS.y += dP.y; }                               \
        const int spe = dup ? 32 : sp;                                         \
        float2 x0 = bins[tid][s];                                              \
        float2 x1 = bins[tid][spe];                                            \
        x0.x += dS.x; x0.y += dS.y;                                            \
        x1.x += dP.x; x1.y += dP.y;                                            \
        bins[tid][s]   = x0;                                                   \
        bins[tid][spe] = x1;                                                   \
    }

#define PROCQ(S) { ROUND(m##S.x, u##S.x, v##S.x) ROUND(m##S.y, u##S.y, v##S.y) \
                   ROUND(m##S.z, u##S.z, v##S.z) ROUND(m##S.w, u##S.w, v##S.w) }

    int4 mA, mB; float4 uA, vA, uB, vB;
    LOADP(A, 0)
    LOADP(B, 1)
    for (int it = 0; it < ITERS; it += 2) {
        PROCQ(A)
        if (it + 2 < ITERS) LOADP(A, it + 2)
        PROCQ(B)
        if (it + 3 < ITERS) LOADP(B, it + 3)
    }

    __syncthreads();   // one wave: cheap; makes cross-lane LDS reads safe

    // Reduce: 128 (seg,comp) pairs; comp 0=cnt(even,x) 1=su(even,y)
    //                                     2=sv(odd,x)  3=s2(odd,y)
    const float* bf = (const float*)bins;
    #pragma unroll
    for (int h = 0; h < 2; ++h) {
        const int p = tid + h * 64;          // 0..127
        const int s = p >> 2, c = p & 3;
        const int parr = c >> 1;
        const int comp = c & 1;
        float sum = 0.0f;
        #pragma unroll
        for (int j = 0; j < 32; ++j)
            sum += bf[((2 * j + parr) * ROWW + s) * 2 + comp];
        unsafeAtomicAdd(&acc[((size_t)b * NSEG + s) * 4 + c], sum);
    }
}

__global__ __launch_bounds__(BATCH * NSEG) void ovl_finalize(
    const float* __restrict__ acc,   // [B*S, 4]
    float* __restrict__ out)         // scalar
{
    const int tid = threadIdx.x;     // 0..511, one per global segment id
    const float cnt = acc[tid * 4 + 0];
    const float su  = acc[tid * 4 + 1];
    const float sv  = acc[tid * 4 + 2];
    const float s2  = acc[tid * 4 + 3];

    const bool is_bg = (tid & (NSEG - 1)) == 0;
    const bool valid = (cnt >= MIN_PIX) && !is_bg;

    const float safe_cnt = fmaxf(cnt, 1.0f);
    const float denom = fmaxf(cnt - 1.0f, 1.0f);
    const float var_sum = (s2 - (su * su + sv * sv) / safe_cnt) / denom;

    float t = valid ? var_sum : 0.0f;
    float n = valid ? 1.0f : 0.0f;

    #pragma unroll
    for (int off = 32; off >= 1; off >>= 1) {
        t += __shfl_down(t, off, 64);
        n += __shfl_down(n, off, 64);
    }

    __shared__ float st[8], sn[8];
    const int wave = tid >> 6;
    const int lane = tid & 63;
    if (lane == 0) { st[wave] = t; sn[wave] = n; }
    __syncthreads();

    if (tid == 0) {
        float tot = 0.0f, ntot = 0.0f;
        #pragma unroll
        for (int w = 0; w < 8; ++w) { tot += st[w]; ntot += sn[w]; }
        out[0] = (ntot > 0.0f) ? (tot / fmaxf(ntot, 1.0f)) : 0.0f;
    }
}

extern "C" void kernel_launch(void* const* d_in, const int* in_sizes, int n_in,
                              void* d_out, int out_size, void* d_ws, size_t ws_size,
                              hipStream_t stream) {
    const float* flow = (const float*)d_in[0];
    const int* masks  = (const int*)d_in[1];
    float* out = (float*)d_out;
    float* acc = (float*)d_ws;

    hipMemsetAsync(acc, 0, ACC_FLOATS * sizeof(float), stream);

    ovl_accum<<<BATCH * BLOCKS_PER_BATCH, THREADS, 0, stream>>>(flow, masks, acc);
    ovl_finalize<<<1, BATCH * NSEG, 0, stream>>>(acc, out);
}